// Round 4
// baseline (244.972 us; speedup 1.0000x reference)
//
#include <hip/hip_runtime.h>
#include <math.h>

// Problem: B=8, C=64, T=16, H=64, W=64, text_dim=768
// out[b,c,:,h,w] = D^T diag(w[b,c,:]) D @ r[b,c,:,h,w]
// w[b, c*16+k] = sigmoid(E_txt[b] . Wf[c*16+k] + bf[c*16+k])

#define HW4 1024         // H*W/4 (float4 units)

typedef float f4 __attribute__((ext_vector_type(4)));

// ---------- Kernel 1: gate + M build -> M[bc][16][16] (natural [t][k]) ----------
// 512 blocks x 256 threads. Thread (krow = tid>>4, sub = tid&15):
// gate dot for row krow (12 f4 of the 192), 16-lane shfl reduce, sigmoid,
// then M[krow][sub] = sum_k D[k][krow]*w[k]*D[k][sub].
// Bitwise-identical arithmetic to the R3 fused prologue (same thread, same
// fmaf chain); only the output layout is the natural [t*16+k].
__global__ __launch_bounds__(256) void gateM_kernel(
    const float* __restrict__ E,    // (8, 768)
    const float* __restrict__ Wf,   // (1024, 768)
    const float* __restrict__ bf,   // (1024,)
    float* __restrict__ Mout)       // (512, 256)
{
    __shared__ float Dl[16][16];
    __shared__ float wv[16];
    const int tid  = threadIdx.x;
    const int bc   = blockIdx.x;         // 0..511
    const int b    = bc >> 6;
    const int c    = bc & 63;
    const int krow = tid >> 4;
    const int sub  = tid & 15;

    const f4* W4 = (const f4*)Wf + (size_t)(c * 16 + krow) * 192 + sub;
    const f4* E4 = (const f4*)E + b * 192 + sub;
    float p0 = 0.f, p1 = 0.f, p2 = 0.f, p3 = 0.f;
#pragma unroll
    for (int j = 0; j < 12; j += 4) {
        f4 w0 = W4[16*(j+0)], e0 = E4[16*(j+0)];
        f4 w1 = W4[16*(j+1)], e1 = E4[16*(j+1)];
        f4 w2 = W4[16*(j+2)], e2 = E4[16*(j+2)];
        f4 w3 = W4[16*(j+3)], e3 = E4[16*(j+3)];
        p0 = fmaf(w0.x,e0.x,p0); p0 = fmaf(w0.y,e0.y,p0);
        p0 = fmaf(w0.z,e0.z,p0); p0 = fmaf(w0.w,e0.w,p0);
        p1 = fmaf(w1.x,e1.x,p1); p1 = fmaf(w1.y,e1.y,p1);
        p1 = fmaf(w1.z,e1.z,p1); p1 = fmaf(w1.w,e1.w,p1);
        p2 = fmaf(w2.x,e2.x,p2); p2 = fmaf(w2.y,e2.y,p2);
        p2 = fmaf(w2.z,e2.z,p2); p2 = fmaf(w2.w,e2.w,p2);
        p3 = fmaf(w3.x,e3.x,p3); p3 = fmaf(w3.y,e3.y,p3);
        p3 = fmaf(w3.z,e3.z,p3); p3 = fmaf(w3.w,e3.w,p3);
    }
    float p = (p0 + p1) + (p2 + p3);
    p += __shfl_xor(p, 1, 64);
    p += __shfl_xor(p, 2, 64);
    p += __shfl_xor(p, 4, 64);
    p += __shfl_xor(p, 8, 64);

    Dl[krow][sub] = (krow == 0)
        ? 0.25f
        : cospif((sub + 0.5f) * (float)krow * (1.0f / 16.0f)) * 0.35355339059327373f;
    if (sub == 0) {
        float s = p + bf[c * 16 + krow];
        wv[krow] = 1.0f / (1.0f + expf(-s));
    }
    __syncthreads();

    float s = 0.f;
#pragma unroll
    for (int k = 0; k < 16; ++k)
        s = fmaf(Dl[k][krow] * wv[k], Dl[k][sub], s);
    Mout[bc * 256 + tid] = s;     // M[t=krow][k=sub], coalesced
}

// ---------- Kernel 2: pure streaming transform, t-major, store-per-t ----------
// 2048 blocks x 256 threads. bc = blk>>2; block covers a contiguous 4 KB
// span of each of the 16 rows (col = (blk&3)*256 + tid).
// x[16] loaded up front (issued before the M-LDS barrier); then per t:
// 4 uniform ds_read_b128 of M row + 64 FMAs + ONE store. Writes are spread
// uniformly through the compute instead of bursting at wave end.
// Accumulation order per output (k ascending) identical to prior rounds.
__global__ __launch_bounds__(256, 4) void mod_kernel(
    const float* __restrict__ r,     // (512, 16, 4096)
    const float* __restrict__ M,     // (512, 256)
    float* __restrict__ out)
{
    __shared__ __align__(16) float Ms[256];   // Ms[t*16+k] = M[t][k]
    const int tid = threadIdx.x;
    const int bc  = blockIdx.x >> 2;
    const int col = (blockIdx.x & 3) * 256 + tid;   // f4 index in [0,1024)

    const size_t base = (size_t)bc * (16 * 4096);
    const f4* rp = (const f4*)(r + base);
    f4*       op = (f4*)(out + base);

    // issue all 16 x loads first (independent of LDS; hide under M stage)
    f4 x[16];
#pragma unroll
    for (int k = 0; k < 16; ++k)
        x[k] = rp[k * HW4 + col];

    if (tid < 64)
        ((f4*)Ms)[tid] = ((const f4*)(M + bc * 256))[tid];
    __syncthreads();

#pragma unroll
    for (int t = 0; t < 16; ++t) {
        const f4* Mt = (const f4*)(Ms + t * 16);
        f4 y = (f4){0.f, 0.f, 0.f, 0.f};
#pragma unroll
        for (int k4 = 0; k4 < 4; ++k4) {
            f4 m = Mt[k4];          // M[t][4k4 .. 4k4+3], uniform broadcast
            f4 x0 = x[4*k4 + 0], x1 = x[4*k4 + 1];
            f4 x2 = x[4*k4 + 2], x3 = x[4*k4 + 3];
            y.x = fmaf(m.x, x0.x, y.x); y.y = fmaf(m.x, x0.y, y.y);
            y.z = fmaf(m.x, x0.z, y.z); y.w = fmaf(m.x, x0.w, y.w);
            y.x = fmaf(m.y, x1.x, y.x); y.y = fmaf(m.y, x1.y, y.y);
            y.z = fmaf(m.y, x1.z, y.z); y.w = fmaf(m.y, x1.w, y.w);
            y.x = fmaf(m.z, x2.x, y.x); y.y = fmaf(m.z, x2.y, y.y);
            y.z = fmaf(m.z, x2.z, y.z); y.w = fmaf(m.z, x2.w, y.w);
            y.x = fmaf(m.w, x3.x, y.x); y.y = fmaf(m.w, x3.y, y.y);
            y.z = fmaf(m.w, x3.z, y.z); y.w = fmaf(m.w, x3.w, y.w);
        }
        op[t * HW4 + col] = y;      // one store per t: smooth write stream
    }
}

extern "C" void kernel_launch(void* const* d_in, const int* in_sizes, int n_in,
                              void* d_out, int out_size, void* d_ws, size_t ws_size,
                              hipStream_t stream) {
    const float* r  = (const float*)d_in[0];   // 33554432
    const float* E  = (const float*)d_in[1];   // 6144
    const float* Wf = (const float*)d_in[2];   // 786432
    const float* bf = (const float*)d_in[3];   // 1024
    float* out = (float*)d_out;
    float* M   = (float*)d_ws;                  // 512*256 floats

    gateM_kernel<<<512,  256, 0, stream>>>(E, Wf, bf, M);
    mod_kernel  <<<2048, 256, 0, stream>>>(r, M, out);
}

// Round 5
// 244.403 us; speedup vs baseline: 1.0023x; 1.0023x over previous
//
#include <hip/hip_runtime.h>
#include <math.h>

// Problem: B=8, C=64, T=16, H=64, W=64, text_dim=768
// out[b,c,:,h,w] = D^T diag(w[b,c,:]) D @ r[b,c,:,h,w]
// w[b, c*16+k] = sigmoid(E_txt[b] . Wf[c*16+k] + bf[c*16+k])

#define HW4 1024         // H*W/4 (float4 units)

typedef float f4 __attribute__((ext_vector_type(4)));

// ---------- Kernel 1: gate + M build -> M[bc][16][16] (natural [t][k]) ----------
// UNCHANGED from R4 (bitwise-identical M).
__global__ __launch_bounds__(256) void gateM_kernel(
    const float* __restrict__ E,    // (8, 768)
    const float* __restrict__ Wf,   // (1024, 768)
    const float* __restrict__ bf,   // (1024,)
    float* __restrict__ Mout)       // (512, 256)
{
    __shared__ float Dl[16][16];
    __shared__ float wv[16];
    const int tid  = threadIdx.x;
    const int bc   = blockIdx.x;         // 0..511
    const int b    = bc >> 6;
    const int c    = bc & 63;
    const int krow = tid >> 4;
    const int sub  = tid & 15;

    const f4* W4 = (const f4*)Wf + (size_t)(c * 16 + krow) * 192 + sub;
    const f4* E4 = (const f4*)E + b * 192 + sub;
    float p0 = 0.f, p1 = 0.f, p2 = 0.f, p3 = 0.f;
#pragma unroll
    for (int j = 0; j < 12; j += 4) {
        f4 w0 = W4[16*(j+0)], e0 = E4[16*(j+0)];
        f4 w1 = W4[16*(j+1)], e1 = E4[16*(j+1)];
        f4 w2 = W4[16*(j+2)], e2 = E4[16*(j+2)];
        f4 w3 = W4[16*(j+3)], e3 = E4[16*(j+3)];
        p0 = fmaf(w0.x,e0.x,p0); p0 = fmaf(w0.y,e0.y,p0);
        p0 = fmaf(w0.z,e0.z,p0); p0 = fmaf(w0.w,e0.w,p0);
        p1 = fmaf(w1.x,e1.x,p1); p1 = fmaf(w1.y,e1.y,p1);
        p1 = fmaf(w1.z,e1.z,p1); p1 = fmaf(w1.w,e1.w,p1);
        p2 = fmaf(w2.x,e2.x,p2); p2 = fmaf(w2.y,e2.y,p2);
        p2 = fmaf(w2.z,e2.z,p2); p2 = fmaf(w2.w,e2.w,p2);
        p3 = fmaf(w3.x,e3.x,p3); p3 = fmaf(w3.y,e3.y,p3);
        p3 = fmaf(w3.z,e3.z,p3); p3 = fmaf(w3.w,e3.w,p3);
    }
    float p = (p0 + p1) + (p2 + p3);
    p += __shfl_xor(p, 1, 64);
    p += __shfl_xor(p, 2, 64);
    p += __shfl_xor(p, 4, 64);
    p += __shfl_xor(p, 8, 64);

    Dl[krow][sub] = (krow == 0)
        ? 0.25f
        : cospif((sub + 0.5f) * (float)krow * (1.0f / 16.0f)) * 0.35355339059327373f;
    if (sub == 0) {
        float s = p + bf[c * 16 + krow];
        wv[krow] = 1.0f / (1.0f + expf(-s));
    }
    __syncthreads();

    float s = 0.f;
#pragma unroll
    for (int k = 0; k < 16; ++k)
        s = fmaf(Dl[k][krow] * wv[k], Dl[k][sub], s);
    Mout[bc * 256 + tid] = s;     // M[t=krow][k=sub], coalesced
}

// ---------- Kernel 2: streaming transform, x PINNED in VGPRs ----------
// 2048 blocks x 256 threads. bc = blk>>2; col = (blk&3)*256 + tid.
// Order: M->LDS stage + barrier FIRST (so the barrier's vmcnt(0) drain
// doesn't serialize the x stream), THEN the 16 x loads, pinned via opaque
// asm so the compiler cannot rematerialize them as per-t reloads (R4's
// VGPR=44 pathology). t-major compute, one store per t (smooth writes).
// Accumulation order per output (k ascending) identical to prior rounds.
__global__ __launch_bounds__(256, 4) void mod_kernel(
    const float* __restrict__ r,     // (512, 16, 4096)
    const float* __restrict__ M,     // (512, 256)
    float* __restrict__ out)
{
    __shared__ __align__(16) float Ms[256];   // Ms[t*16+k] = M[t][k]
    const int tid = threadIdx.x;
    const int bc  = blockIdx.x >> 2;
    const int col = (blockIdx.x & 3) * 256 + tid;   // f4 index in [0,1024)

    const size_t base = (size_t)bc * (16 * 4096);
    const f4* rp = (const f4*)(r + base);
    f4*       op = (f4*)(out + base);

    // ---- stage M first; its barrier drains only this one load ----
    if (tid < 64)
        ((f4*)Ms)[tid] = ((const f4*)(M + bc * 256))[tid];
    __syncthreads();

    // ---- 16 x loads, pinned resident in VGPRs ----
    f4 x[16];
#pragma unroll
    for (int k = 0; k < 16; ++k)
        x[k] = rp[k * HW4 + col];
#pragma unroll
    for (int k = 0; k < 16; ++k)
        asm volatile("" : "+v"(x[k]));   // opaque: forbids global rematerialization

#pragma unroll
    for (int t = 0; t < 16; ++t) {
        const f4* Mt = (const f4*)(Ms + t * 16);
        f4 y = (f4){0.f, 0.f, 0.f, 0.f};
#pragma unroll
        for (int k4 = 0; k4 < 4; ++k4) {
            f4 m = Mt[k4];          // M[t][4k4 .. 4k4+3], uniform broadcast
            f4 x0 = x[4*k4 + 0], x1 = x[4*k4 + 1];
            f4 x2 = x[4*k4 + 2], x3 = x[4*k4 + 3];
            y.x = fmaf(m.x, x0.x, y.x); y.y = fmaf(m.x, x0.y, y.y);
            y.z = fmaf(m.x, x0.z, y.z); y.w = fmaf(m.x, x0.w, y.w);
            y.x = fmaf(m.y, x1.x, y.x); y.y = fmaf(m.y, x1.y, y.y);
            y.z = fmaf(m.y, x1.z, y.z); y.w = fmaf(m.y, x1.w, y.w);
            y.x = fmaf(m.z, x2.x, y.x); y.y = fmaf(m.z, x2.y, y.y);
            y.z = fmaf(m.z, x2.z, y.z); y.w = fmaf(m.z, x2.w, y.w);
            y.x = fmaf(m.w, x3.x, y.x); y.y = fmaf(m.w, x3.y, y.y);
            y.z = fmaf(m.w, x3.z, y.z); y.w = fmaf(m.w, x3.w, y.w);
        }
        op[t * HW4 + col] = y;      // one store per t: smooth write stream
    }
}

extern "C" void kernel_launch(void* const* d_in, const int* in_sizes, int n_in,
                              void* d_out, int out_size, void* d_ws, size_t ws_size,
                              hipStream_t stream) {
    const float* r  = (const float*)d_in[0];   // 33554432
    const float* E  = (const float*)d_in[1];   // 6144
    const float* Wf = (const float*)d_in[2];   // 786432
    const float* bf = (const float*)d_in[3];   // 1024
    float* out = (float*)d_out;
    float* M   = (float*)d_ws;                  // 512*256 floats

    gateM_kernel<<<512,  256, 0, stream>>>(E, Wf, bf, M);
    mod_kernel  <<<2048, 256, 0, stream>>>(r, M, out);
}